// Round 1
// baseline (130.469 us; speedup 1.0000x reference)
//
#include <hip/hip_runtime.h>
#include <cstdint>
#include <cstddef>

#define N_PTS 4096
#define KDIM  512
#define NFEAT 5

typedef __attribute__((ext_vector_type(8))) short bf16x8;   // 8 bf16 = 4 VGPRs
typedef __attribute__((ext_vector_type(4))) float f32x4;

// round-to-nearest-even fp32 -> bf16 (inputs are finite normals; no NaN path)
__device__ inline short f2bf(float f) {
  union { float f; uint32_t u; } v; v.f = f;
  uint32_t r = (v.u + 0x7fffu + ((v.u >> 16) & 1u)) >> 16;
  return (short)r;
}

// async global->LDS, 16B per lane (dest must be wave-uniform base + lane*16)
__device__ inline void load_lds16(const void* g, void* l) {
  __builtin_amdgcn_global_load_lds(
      (const __attribute__((address_space(1))) void*)g,
      (__attribute__((address_space(3))) void*)l, 16, 0, 0);
}

// ---------------------------------------------------------------------------
// Kernel 1: convert X (fp32) -> bf16, and compute per-row squared norms (fp32)
// one block per row; 256 threads x 2 elements = 512
// ---------------------------------------------------------------------------
__global__ __launch_bounds__(256) void prep_kernel(const float* __restrict__ X,
                                                   short* __restrict__ Xb,
                                                   float* __restrict__ sq) {
  const int row = blockIdx.x;
  const int t = threadIdx.x;
  const float2 v = ((const float2*)(X + (size_t)row * KDIM))[t];
  short2 b;
  b.x = f2bf(v.x);
  b.y = f2bf(v.y);
  ((short2*)(Xb + (size_t)row * KDIM))[t] = b;
  float s = v.x * v.x + v.y * v.y;
#pragma unroll
  for (int off = 32; off; off >>= 1) s += __shfl_down(s, off);
  __shared__ float ws[4];
  if ((t & 63) == 0) ws[t >> 6] = s;
  __syncthreads();
  if (t == 0) sq[row] = ws[0] + ws[1] + ws[2] + ws[3];
}

// ---------------------------------------------------------------------------
// Kernel 2: D[i][j] = sqrt(max(sq_i + sq_j - 2*dot(x_i,x_j), 0)), diag forced 0
// plus global sum of D via per-block atomicAdd.
// 128x128 tile per 256-thread block (4 waves, each wave 64x64), BK=32,
// mfma_f32_16x16x32_bf16, global_load_lds width=16 staging (m97 structure).
// ---------------------------------------------------------------------------
__global__ __launch_bounds__(256, 2) void dist_kernel(
    const short* __restrict__ Xb, const float* __restrict__ sq,
    float* __restrict__ D, float* __restrict__ gsum) {
  __shared__ short As[128 * 32];   // 8 KB, row-major [row][k]
  __shared__ short Bs[128 * 32];   // 8 KB
  __shared__ float red[4];

  const int tid = threadIdx.x;
  const int lane = tid & 63;
  const int wid = tid >> 6;
  const int wave_m = wid >> 1, wave_n = wid & 1;
  const int lhi = lane >> 4, llo = lane & 15;
  const int bm = blockIdx.y, bn = blockIdx.x;

  f32x4 acc[4][4];
#pragma unroll
  for (int i = 0; i < 4; ++i)
#pragma unroll
    for (int j = 0; j < 4; ++j) acc[i][j] = (f32x4){0.f, 0.f, 0.f, 0.f};

  // staging: thread t covers tile byte offset t*16 (+4096 for rows 64..127)
  const int srow = tid >> 2;         // 0..63
  const int scol = (tid & 3) * 8;    // k element offset
  const size_t ga0 = (size_t)(bm * 128 + srow) * KDIM + scol;
  const size_t gb0 = (size_t)(bn * 128 + srow) * KDIM + scol;

  for (int kt = 0; kt < KDIM / 32; ++kt) {
    const int koff = kt * 32;
    load_lds16(Xb + ga0 + koff,             (char*)As + tid * 16);
    load_lds16(Xb + ga0 + 64 * KDIM + koff, (char*)As + 4096 + tid * 16);
    load_lds16(Xb + gb0 + koff,             (char*)Bs + tid * 16);
    load_lds16(Xb + gb0 + 64 * KDIM + koff, (char*)Bs + 4096 + tid * 16);
    __syncthreads();   // compiler emits s_waitcnt vmcnt(0) before s_barrier

    bf16x8 a[4], b[4];
#pragma unroll
    for (int i = 0; i < 4; ++i) {
      a[i] = *(const bf16x8*)&As[(wave_m * 64 + i * 16 + llo) * 32 + lhi * 8];
      b[i] = *(const bf16x8*)&Bs[(wave_n * 64 + i * 16 + llo) * 32 + lhi * 8];
    }
#pragma unroll
    for (int i = 0; i < 4; ++i)
#pragma unroll
      for (int j = 0; j < 4; ++j)
        acc[i][j] =
            __builtin_amdgcn_mfma_f32_16x16x32_bf16(a[i], b[j], acc[i][j], 0, 0, 0);
    __syncthreads();
  }

  // epilogue: C/D layout col=lane&15, row=(lane>>4)*4+reg
  float lsum = 0.f;
  const int gi0 = bm * 128 + wave_m * 64;
  const int gj0 = bn * 128 + wave_n * 64;
#pragma unroll
  for (int i = 0; i < 4; ++i) {
#pragma unroll
    for (int r = 0; r < 4; ++r) {
      const int gi = gi0 + i * 16 + lhi * 4 + r;
      const float sqi = sq[gi];
#pragma unroll
      for (int j = 0; j < 4; ++j) {
        const int gj = gj0 + j * 16 + llo;
        float d2 = sqi + sq[gj] - 2.f * acc[i][j][r];
        float dd = sqrtf(fmaxf(d2, 0.f));
        if (gi == gj) dd = 0.f;  // bf16 self-dot noise under sqrt: force exact 0
        D[(size_t)gi * N_PTS + gj] = dd;
        lsum += dd;
      }
    }
  }
#pragma unroll
  for (int off = 32; off; off >>= 1) lsum += __shfl_down(lsum, off);
  if (lane == 0) red[wid] = lsum;
  __syncthreads();
  if (tid == 0) atomicAdd(gsum, red[0] + red[1] + red[2] + red[3]);
}

// ---------------------------------------------------------------------------
// Kernel 3: out = sum_f exp(-d / (bw * mult_f)), in place over D, float4 I/O
// ---------------------------------------------------------------------------
__global__ __launch_bounds__(256) void rbf_kernel(float* __restrict__ D,
                                                  const float* __restrict__ gsum,
                                                  const float* __restrict__ mult) {
  const float bw = *gsum * (1.0f / ((float)N_PTS * (float)(N_PTS - 1)));
  float c[NFEAT];
#pragma unroll
  for (int f = 0; f < NFEAT; ++f) c[f] = -1.0f / (bw * mult[f]);

  const size_t total = (size_t)N_PTS * N_PTS / 4;
  const size_t stride = (size_t)gridDim.x * blockDim.x;
  float4* D4 = (float4*)D;
  for (size_t idx = (size_t)blockIdx.x * blockDim.x + threadIdx.x; idx < total;
       idx += stride) {
    float4 v = D4[idx];
    float4 o = {0.f, 0.f, 0.f, 0.f};
#pragma unroll
    for (int f = 0; f < NFEAT; ++f) {
      o.x += __expf(v.x * c[f]);
      o.y += __expf(v.y * c[f]);
      o.z += __expf(v.z * c[f]);
      o.w += __expf(v.w * c[f]);
    }
    D4[idx] = o;
  }
}

extern "C" void kernel_launch(void* const* d_in, const int* in_sizes, int n_in,
                              void* d_out, int out_size, void* d_ws, size_t ws_size,
                              hipStream_t stream) {
  const float* X = (const float*)d_in[0];
  const float* mult = (const float*)d_in[1];
  float* D = (float*)d_out;

  // ws layout: [0,4) global distance sum | [1024, 1024+16KB) sq | [17408, +4MB) Xb
  char* ws = (char*)d_ws;
  float* gsum = (float*)ws;
  float* sq = (float*)(ws + 1024);
  short* Xb = (short*)(ws + 1024 + N_PTS * sizeof(float));  // 17408, 256B aligned

  hipMemsetAsync(gsum, 0, 256, stream);
  prep_kernel<<<N_PTS, 256, 0, stream>>>(X, Xb, sq);
  dist_kernel<<<dim3(N_PTS / 128, N_PTS / 128), 256, 0, stream>>>(Xb, sq, D, gsum);
  rbf_kernel<<<4096, 256, 0, stream>>>(D, gsum, mult);
}